// Round 9
// baseline (96.862 us; speedup 1.0000x reference)
//
#include <hip/hip_runtime.h>
#include <hip/hip_bf16.h>

#define B_ 16
#define N_ 64
#define C_ 128
#define H_ 64
#define W_ 64
#define HW_ (H_ * W_)
#define OUT_CH_ 256
#define MAX_GRID_ 16
#define SCALE_ 0.125f

__device__ __forceinline__ unsigned int packbf2(float lo, float hi) {
  __hip_bfloat162 h = __float22bfloat162_rn(float2{lo, hi});
  return *(unsigned int*)&h;
}

// ---------------------------------------------------------------------------
// Kernel 1: z [B, C, HW] fp32 -> zf [B, HW, C/2] bf16-pairs (u32), plus
// (blockIdx.y==16 slab) W [OUT_CH, C] -> Wt [C, OUT_CH] fp32.
// ---------------------------------------------------------------------------
__global__ __launch_bounds__(256) void transpose_kernel(
    const float* __restrict__ z, const float* __restrict__ Wm,
    unsigned int* __restrict__ zf, float* __restrict__ Wt) {
  __shared__ unsigned int tile32[128 * 65];  // [p][c2], pad 65
  const int t = threadIdx.x;

  if (blockIdx.y == 16) {   // W-transpose slab
    float* ft = (float*)tile32;             // 32 x 33
    int x  = blockIdx.x;                    // 0..31
    int ot = x & 7, ct = x >> 3;
    int j = t & 31, i0 = t >> 5;
#pragma unroll
    for (int k = 0; k < 4; ++k) {
      int i = i0 + k * 8;
      ft[i * 33 + j] = Wm[(size_t)(ot * 32 + i) * C_ + ct * 32 + j];
    }
    __syncthreads();
#pragma unroll
    for (int k = 0; k < 4; ++k) {
      int i = i0 + k * 8;
      Wt[(size_t)(ct * 32 + i) * OUT_CH_ + ot * 32 + j] = ft[j * 33 + i];
    }
    return;
  }

  const int b  = blockIdx.y;
  const int pt = blockIdx.x;  // HW tile, 0..31
  const float* zb = z + (size_t)b * C_ * HW_ + pt * 128;
#pragma unroll
  for (int iter = 0; iter < 8; ++iter) {
    int idx = iter * 256 + t;        // 0..2047
    int c2  = idx >> 5;              // channel pair 0..63
    int p4  = (idx & 31) << 2;       // 0,4,...,124
    const float* r0 = zb + (size_t)(c2 * 2) * HW_ + p4;
    float4 a = *(const float4*)r0;
    float4 c = *(const float4*)(r0 + HW_);
    tile32[(p4 + 0) * 65 + c2] = packbf2(a.x, c.x);
    tile32[(p4 + 1) * 65 + c2] = packbf2(a.y, c.y);
    tile32[(p4 + 2) * 65 + c2] = packbf2(a.z, c.z);
    tile32[(p4 + 3) * 65 + c2] = packbf2(a.w, c.w);
  }
  __syncthreads();

  unsigned int* zfb = zf + (size_t)b * HW_ * 64 + (size_t)pt * 128 * 64;
#pragma unroll
  for (int iter = 0; iter < 8; ++iter) {
    int idx = iter * 256 + t;        // 0..2047
    int p   = idx >> 4;              // 0..127
    int q   = (idx & 15) << 2;       // 0,4,...,60
    uint4 u = *(const uint4*)&tile32[p * 65 + q];
    *(uint4*)(zfb + (size_t)p * 64 + q) = u;
  }
}

// ---------------------------------------------------------------------------
// Kernel 2: fused ROI-align + reduce + Linear, 2 ROIs per block.
// 512 blocks x 512 thr (2 blocks/CU, 16 waves/CU). Each wave gathers both
// ROIs sequentially (block time ~ sum of 2 ROIs -> shorter tail). Metadata
// for both ROIs precomputed in LDS. Epilogue: direct per-(oc, roi) Linear,
// Wt read once per block (both roi-halves hit same addresses -> L1).
// ---------------------------------------------------------------------------
__global__ __launch_bounds__(512) void roi_fused_kernel(
    const unsigned int* __restrict__ zf,     // [B, HW, 64] bf16-pairs
    const float* __restrict__ boxes,         // [B, N, 4]
    const float* __restrict__ Wt,            // [C, OUT_CH]
    const float* __restrict__ bias,          // [OUT_CH]
    float* __restrict__ out)                 // [B*N, OUT_CH]
{
  int bid  = blockIdx.x;                    // 0..511
  int xcd  = bid & 7;
  int slot = bid >> 3;                      // 0..63
  int img  = xcd | ((slot >> 5) << 3);      // 0..15 (image -> XCD class)
  int pr   = slot & 31;                     // roi-pair within image
  int roi0 = img * N_ + pr * 2;             // ROIs {roi0, roi0+1}

  int t    = threadIdx.x;
  int wv   = t >> 6;         // wave 0..7
  int lane = t & 63;
  int half = lane >> 5;      // gx parity
  int cq   = lane & 31;      // channel quad (4 channels)

  // --- per-ROI scalars (both ROIs) ---
  __shared__ float4 xmeta[2][16];
  __shared__ float4 ymeta[2][16];
  __shared__ float  cnt_inv[2];
  __shared__ int    dims[2][2];             // gw, gh

  // meta build: t<32 -> xmeta[r][g]; t in [64,96) -> ymeta[r][g]
  if (t < 32 || (t >= 64 && t < 96)) {
    int isY = t >> 6;
    int tt  = t & 31;
    int r   = tt >> 4;
    int g   = tt & 15;
    float4 bx = ((const float4*)boxes)[roi0 + r];
    float x1 = bx.x * SCALE_ - 0.5f;
    float y1 = bx.y * SCALE_ - 0.5f;
    float roi_w = bx.z * SCALE_ - 0.5f - x1;
    float roi_h = bx.w * SCALE_ - 0.5f - y1;
    float gwf = fminf(fmaxf(ceilf(roi_w), 1.0f), (float)MAX_GRID_);
    float ghf = fminf(fmaxf(ceilf(roi_h), 1.0f), (float)MAX_GRID_);
    if (!isY) {
      int gw = (int)gwf;
      float stepx = roi_w / gwf;
      float sx = x1 + ((float)g + 0.5f) * stepx;
      float v  = (g < gw && sx > -1.0f && sx < (float)W_) ? 1.0f : 0.0f;
      float cx = fmaxf(sx, 0.0f);
      int xl = (int)cx;
      xl = xl < (W_ - 1) ? xl : (W_ - 1);
      int xh = (xl + 1) < (W_ - 1) ? (xl + 1) : (W_ - 1);
      if (xl >= W_ - 1) cx = (float)xl;
      float fx = cx - (float)xl;
      float4 m;
      m.x = __int_as_float(xl << 6);
      m.y = __int_as_float(xh << 6);
      m.z = (1.0f - fx) * v;
      m.w = fx * v;
      xmeta[r][g] = m;
      if (g == 0) {
        dims[r][0] = gw;
        cnt_inv[r] = 1.0f / (ghf * gwf);
      }
    } else {
      int gh = (int)ghf;
      float stepy = roi_h / ghf;
      float sy = y1 + ((float)g + 0.5f) * stepy;
      float v  = (g < gh && sy > -1.0f && sy < (float)H_) ? 1.0f : 0.0f;
      float cy = fmaxf(sy, 0.0f);
      int yl = (int)cy;
      yl = yl < (H_ - 1) ? yl : (H_ - 1);
      int yh = (yl + 1) < (H_ - 1) ? (yl + 1) : (H_ - 1);
      if (yl >= H_ - 1) cy = (float)yl;
      float fy = cy - (float)yl;
      float4 m;
      m.x = __int_as_float(yl * (W_ * 64));
      m.y = __int_as_float(yh * (W_ * 64));
      m.z = (1.0f - fy) * v;
      m.w = fy * v;
      ymeta[r][g] = m;
      if (g == 0) dims[r][1] = gh;
    }
  }
  __syncthreads();

  const unsigned int* zb = zf + (size_t)img * (HW_ * 64) + (cq << 1);

  __shared__ float red[2][16][128];
  __shared__ float feat[2][128];

#pragma unroll
  for (int r = 0; r < 2; ++r) {
    int gw = dims[r][0];
    int gh = dims[r][1];
    float a0 = 0.0f, a1 = 0.0f, a2 = 0.0f, a3 = 0.0f;
    for (int gy = wv; gy < gh; gy += 8) {
      float4 ym = ymeta[r][gy];            // wave-uniform broadcast
      int yloff = __float_as_int(ym.x);
      int yhoff = __float_as_int(ym.y);
      float ah = ym.z, af = ym.w;

      for (int gxp = 0; gxp < gw; gxp += 2) {
        int gx = gxp + half;               // gx==gw (odd gw) -> weight 0
        float4 xm = xmeta[r][gx];
        int xloff = __float_as_int(xm.x);
        int xhoff = __float_as_int(xm.y);
        float w11 = ah * xm.z, w12 = ah * xm.w;
        float w21 = af * xm.z, w22 = af * xm.w;

        uint2 v11 = *(const uint2*)(zb + yloff + xloff);
        uint2 v12 = *(const uint2*)(zb + yloff + xhoff);
        uint2 v21 = *(const uint2*)(zb + yhoff + xloff);
        uint2 v22 = *(const uint2*)(zb + yhoff + xhoff);

        a0 += w11 * __uint_as_float(v11.x << 16)
            + w12 * __uint_as_float(v12.x << 16)
            + w21 * __uint_as_float(v21.x << 16)
            + w22 * __uint_as_float(v22.x << 16);
        a1 += w11 * __uint_as_float(v11.x & 0xffff0000u)
            + w12 * __uint_as_float(v12.x & 0xffff0000u)
            + w21 * __uint_as_float(v21.x & 0xffff0000u)
            + w22 * __uint_as_float(v22.x & 0xffff0000u);
        a2 += w11 * __uint_as_float(v11.y << 16)
            + w12 * __uint_as_float(v12.y << 16)
            + w21 * __uint_as_float(v21.y << 16)
            + w22 * __uint_as_float(v22.y << 16);
        a3 += w11 * __uint_as_float(v11.y & 0xffff0000u)
            + w12 * __uint_as_float(v12.y & 0xffff0000u)
            + w21 * __uint_as_float(v21.y & 0xffff0000u)
            + w22 * __uint_as_float(v22.y & 0xffff0000u);
      }
    }
    *(float4*)&red[r][wv * 2 + half][cq << 2] = float4{a0, a1, a2, a3};
  }
  __syncthreads();

  // reduce both ROIs: t<256 -> r = t>>7, c = t&127
  if (t < 256) {
    int r = t >> 7, c = t & 127;
    float s = 0.0f;
#pragma unroll
    for (int j = 0; j < 16; ++j) s += red[r][j][c];
    feat[r][c] = s * cnt_inv[r];
  }
  __syncthreads();

  // Linear: t -> (oc = t&255, r = t>>8); Wt element (k,oc) read by both
  // r-halves at identical addresses (L1 broadcast).
  int oc = t & 255;
  int r  = t >> 8;
  const float* fp = feat[r];
  float a = bias[oc];
#pragma unroll 8
  for (int k = 0; k < C_; ++k)
    a += fp[k] * Wt[(size_t)k * OUT_CH_ + oc];
  out[(size_t)(roi0 + r) * OUT_CH_ + oc] = a;
}

extern "C" void kernel_launch(void* const* d_in, const int* in_sizes, int n_in,
                              void* d_out, int out_size, void* d_ws, size_t ws_size,
                              hipStream_t stream) {
  const float* z     = (const float*)d_in[0];  // [B,C,H,W]
  const float* boxes = (const float*)d_in[1];  // [B,N,4]
  const float* Wm    = (const float*)d_in[2];  // [OUT_CH,C]
  const float* bias  = (const float*)d_in[3];  // [OUT_CH]
  float* out = (float*)d_out;

  char* ws = (char*)d_ws;
  unsigned int* zf = (unsigned int*)ws;                      // 16.78 MB
  float* Wt = (float*)(ws + (size_t)B_ * HW_ * C_ * 2);      // 128 KB

  transpose_kernel<<<dim3(HW_ / 128, B_ + 1), 256, 0, stream>>>(z, Wm, zf, Wt);
  roi_fused_kernel<<<B_ * N_ / 2, 512, 0, stream>>>(zf, boxes, Wt, bias, out);
}